// Round 1
// 1322.776 us; speedup vs baseline: 1.0688x; 1.0688x over previous
//
#include <hip/hip_runtime.h>
#include <math.h>

#define KDIM 65536
#define MATF 262144           // 512*512 floats
#define EPSG 1e-6

using bf16x8 = __attribute__((ext_vector_type(8))) __bf16;
using f32x4  = __attribute__((ext_vector_type(4))) float;

// ---- ws layout ----
// 0      : float M[1024]
// 4096   : double S[16]   (0:n2A 1:n2B 2:trA 3:trB 4:cross)
// 8192   : float G[2*MATF]                       (2 MB)
// 8192+2M: "big" region:
//          Gp[2*nk*MATF] split-K gram partials (nk=32 -> 64 MB; dead after k_gfin)
//          then reused for NS state (10 MB):
//            Yb0(2 mats) Yb1(2) Zb0(2) Zb1(2) W(2), each mat 1 MB fp32

__global__ __launch_bounds__(256) void k_means(const float* __restrict__ X,
                                               const float* __restrict__ Xt,
                                               float* __restrict__ M) {
  const int row = blockIdx.x, inp = blockIdx.y;
  const float4* p = (const float4*)((inp ? Xt : X) + (size_t)row * KDIM);
  double s = 0.0;
  for (int i = threadIdx.x; i < KDIM / 4; i += 256) {
    float4 v = p[i];
    s += (double)v.x + (double)v.y + (double)v.z + (double)v.w;
  }
  __shared__ double sm[256];
  sm[threadIdx.x] = s;
  __syncthreads();
  for (int o = 128; o > 0; o >>= 1) {
    if (threadIdx.x < o) sm[threadIdx.x] += sm[threadIdx.x + o];
    __syncthreads();
  }
  if (threadIdx.x == 0) M[inp * 512 + row] = (float)(sm[0] * (1.0 / KDIM));
}

__device__ __forceinline__ void cvt8(float4 a, float4 b, bf16x8& hi, bf16x8& lo) {
  float f[8] = {a.x, a.y, a.z, a.w, b.x, b.y, b.z, b.w};
#pragma unroll
  for (int e = 0; e < 8; ++e) {
    __bf16 h = (__bf16)f[e];
    hi[e] = h;
    lo[e] = (__bf16)(f[e] - (float)h);
  }
}

// Raw X X^T partials via bf16 split-3 MFMA. 128x128 tiles (upper tri, 10),
// split-K nk chunks. grid (10, nk, 2), 256 threads.
// LDS frag-ordered: slot(row,k) = (row>>4)*64 + (k>>3)*16 + (row&15), bf16x8
// per slot -> frag reads are lane-contiguous 16B (conflict-free).
// Register double-buffer: next 32-k global loads issued right after the first
// barrier so they overlap frag reads + MFMA of the current step.
__global__ __launch_bounds__(256, 2) void k_gram(const float* __restrict__ X,
                                                 const float* __restrict__ Xt,
                                                 float* __restrict__ Gp, int nk) {
  int rem = blockIdx.x, ti = 0;
  while (rem >= 4 - ti) { rem -= 4 - ti; ++ti; }
  const int tj = ti + rem;
  const int chunk = blockIdx.y, inp = blockIdx.z;
  const int chunkv = KDIM / nk;
  const float* __restrict__ A = inp ? Xt : X;
  float* __restrict__ C = Gp + ((size_t)(inp * nk + chunk)) * MATF;
  const bool diag = (ti == tj);

  __shared__ bf16x8 AhV[512], AlV[512], BhV[512], BlV[512];   // 8 KB each

  const int t = threadIdx.x;
  const int srow = t & 127, skh = t >> 7;                 // stage row, k-half
  const int sbase = ((srow >> 4) << 6) + (skh << 5) + (srow & 15);

  const float* pa = A + (size_t)(ti * 128 + srow) * KDIM + (size_t)chunk * chunkv + skh * 16;
  const float* pb = A + (size_t)(tj * 128 + srow) * KDIM + (size_t)chunk * chunkv + skh * 16;

  const int wave = t >> 6, lane = t & 63;
  const int wy = (wave >> 1) * 64, wx = (wave & 1) * 64;

  f32x4 acc[4][4];
#pragma unroll
  for (int i = 0; i < 4; ++i)
#pragma unroll
    for (int j = 0; j < 4; ++j) acc[i][j] = (f32x4){0.f, 0.f, 0.f, 0.f};

  float4 ra0 = *(const float4*)(pa);
  float4 ra1 = *(const float4*)(pa + 4);
  float4 ra2 = *(const float4*)(pa + 8);
  float4 ra3 = *(const float4*)(pa + 12);
  float4 rb0 = {}, rb1 = {}, rb2 = {}, rb3 = {};
  if (!diag) {
    rb0 = *(const float4*)(pb);
    rb1 = *(const float4*)(pb + 4);
    rb2 = *(const float4*)(pb + 8);
    rb3 = *(const float4*)(pb + 12);
  }

  for (int ks = 0; ks < chunkv; ks += 32) {
    {
      bf16x8 h, l;
      cvt8(ra0, ra1, h, l); AhV[sbase] = h; AlV[sbase] = l;
      cvt8(ra2, ra3, h, l); AhV[sbase + 16] = h; AlV[sbase + 16] = l;
      if (!diag) {
        cvt8(rb0, rb1, h, l); BhV[sbase] = h; BlV[sbase] = l;
        cvt8(rb2, rb3, h, l); BhV[sbase + 16] = h; BlV[sbase + 16] = l;
      }
    }
    __syncthreads();
    if (ks + 32 < chunkv) {   // prefetch next step; overlaps with MFMA below
      ra0 = *(const float4*)(pa + ks + 32);
      ra1 = *(const float4*)(pa + ks + 36);
      ra2 = *(const float4*)(pa + ks + 40);
      ra3 = *(const float4*)(pa + ks + 44);
      if (!diag) {
        rb0 = *(const float4*)(pb + ks + 32);
        rb1 = *(const float4*)(pb + ks + 36);
        rb2 = *(const float4*)(pb + ks + 40);
        rb3 = *(const float4*)(pb + ks + 44);
      }
    }
    const bf16x8* __restrict__ Bh = diag ? AhV : BhV;
    const bf16x8* __restrict__ Bl = diag ? AlV : BlV;
    bf16x8 ah[4], al[4], bh[4], bl[4];
#pragma unroll
    for (int g = 0; g < 4; ++g) {
      ah[g] = AhV[((wave >> 1) * 4 + g) * 64 + lane];
      al[g] = AlV[((wave >> 1) * 4 + g) * 64 + lane];
      bh[g] = Bh[((wave & 1) * 4 + g) * 64 + lane];
      bl[g] = Bl[((wave & 1) * 4 + g) * 64 + lane];
    }
#pragma unroll
    for (int i = 0; i < 4; ++i)
#pragma unroll
      for (int j = 0; j < 4; ++j) {
        acc[i][j] = __builtin_amdgcn_mfma_f32_16x16x32_bf16(ah[i], bh[j], acc[i][j], 0, 0, 0);
        acc[i][j] = __builtin_amdgcn_mfma_f32_16x16x32_bf16(al[i], bh[j], acc[i][j], 0, 0, 0);
        acc[i][j] = __builtin_amdgcn_mfma_f32_16x16x32_bf16(ah[i], bl[j], acc[i][j], 0, 0, 0);
      }
    __syncthreads();
  }
  const int r4 = (lane >> 4) * 4, fc = lane & 15;
#pragma unroll
  for (int i = 0; i < 4; ++i) {
    const int grow = ti * 128 + wy + i * 16 + r4;
#pragma unroll
    for (int j = 0; j < 4; ++j) {
      const int gcol = tj * 128 + wx + j * 16 + fc;
#pragma unroll
      for (int r = 0; r < 4; ++r)
        C[(size_t)(grow + r) * 512 + gcol] = acc[i][j][r];
    }
  }
}

// Reduce nk partials (fp64), apply mean correction -K*mi*mj + eps, /K.
// Mirror to lower tri; accumulate ||G||_F^2 and trace.
__global__ __launch_bounds__(256) void k_gfin(const float* __restrict__ Gp,
                                              const float* __restrict__ M,
                                              float* __restrict__ G,
                                              double* __restrict__ S, int nk) {
  const int inp = blockIdx.y;
  const int idx = blockIdx.x * 256 + threadIdx.x;
  const int i = idx >> 9, j = idx & 511;
  double n2 = 0.0, tr = 0.0;
  float* g = G + (size_t)inp * MATF;
  if (i <= j) {
    double sum = 0.0;
    const float* p = Gp + (size_t)inp * nk * MATF + idx;
    for (int c = 0; c < nk; ++c) sum += (double)p[(size_t)c * MATF];
    sum -= 65536.0 * (double)M[inp * 512 + i] * (double)M[inp * 512 + j];
    if (i == j) sum += EPSG;
    float v = (float)(sum * (1.0 / 65536.0));
    g[idx] = v;
    if (i < j) { g[(size_t)j * 512 + i] = v; n2 = 2.0 * (double)v * (double)v; }
    else       { n2 = (double)v * (double)v; tr = (double)v; }
  }
  __shared__ double s1[256], s2[256];
  s1[threadIdx.x] = n2; s2[threadIdx.x] = tr;
  __syncthreads();
  for (int o = 128; o > 0; o >>= 1) {
    if (threadIdx.x < o) { s1[threadIdx.x] += s1[threadIdx.x + o]; s2[threadIdx.x] += s2[threadIdx.x + o]; }
    __syncthreads();
  }
  if (threadIdx.x == 0) { atomicAdd(&S[inp], s1[0]); atomicAdd(&S[2 + inp], s2[0]); }
}

// Y0 = G/norm ; Z1 = 1.5 I - 0.5 Y0 (first NS iteration's Z, since Z0 = I).
__global__ __launch_bounds__(256) void k_nsinit(const float* __restrict__ G,
                                                float* __restrict__ Y0,
                                                float* __restrict__ Z1,
                                                const double* __restrict__ S) {
  const int inp = blockIdx.y;
  const int idx = blockIdx.x * 256 + threadIdx.x;
  const float norm = (float)sqrt(S[inp]);
  const float y = G[(size_t)inp * MATF + idx] / norm;
  Y0[(size_t)inp * MATF + idx] = y;
  Z1[(size_t)inp * MATF + idx] = ((idx >> 9) == (idx & 511)) ? (1.5f - 0.5f * y) : (-0.5f * y);
}

// NS-iteration GEMM via bf16 split-3 MFMA. All NS matrices (Y,Z,W) are
// polynomials in symmetric G -> symmetric, so A@B == A@B^T and both operands
// load ROW-wise (gram-style fragments, no transpose staging). Output is also
// symmetric: compute upper-tri 128x128 tiles (10 of 16) and mirror (mirror
// store is a coalesced float4 per lane). 512 threads = 8 waves of 64x32.
// mode 0: C = acc          (W = Z@Y)
// mode 1: C = 1.5*E - 0.5*acc   (Yn = 1.5Y-0.5*Y@W, Zn = 1.5Z-0.5*W@Z)
__device__ __forceinline__ void ns_gemm(const float* __restrict__ A,
                                        const float* __restrict__ B,
                                        const float* __restrict__ E,
                                        float* __restrict__ C, int mode) {
  int rem = blockIdx.x, ti = 0;
  while (rem >= 4 - ti) { rem -= 4 - ti; ++ti; }
  const int tj = ti + rem;

  __shared__ bf16x8 AhV[512], AlV[512], BhV[512], BlV[512];   // 32 KB

  const int t = threadIdx.x;
  const int srow = t & 127, sko = t >> 7;                 // stage row, k-octet
  const int sslot = ((srow >> 4) << 6) + (sko << 4) + (srow & 15);

  const float* pa = A + (size_t)(ti * 128 + srow) * 512 + sko * 8;
  const float* pb = B + (size_t)(tj * 128 + srow) * 512 + sko * 8;

  const int wave = t >> 6, lane = t & 63;
  const int wy = (wave >> 2) * 64, wx = (wave & 3) * 32;  // 2x4 wave grid

  f32x4 acc[4][2];
#pragma unroll
  for (int i = 0; i < 4; ++i)
#pragma unroll
    for (int j = 0; j < 2; ++j) acc[i][j] = (f32x4){0.f, 0.f, 0.f, 0.f};

  float4 ra0 = *(const float4*)(pa), ra1 = *(const float4*)(pa + 4);
  float4 rb0 = *(const float4*)(pb), rb1 = *(const float4*)(pb + 4);

  for (int ks = 0; ks < 512; ks += 32) {
    {
      bf16x8 h, l;
      cvt8(ra0, ra1, h, l); AhV[sslot] = h; AlV[sslot] = l;
      cvt8(rb0, rb1, h, l); BhV[sslot] = h; BlV[sslot] = l;
    }
    __syncthreads();
    if (ks + 32 < 512) {   // prefetch next k-step (L2-resident operands)
      ra0 = *(const float4*)(pa + ks + 32); ra1 = *(const float4*)(pa + ks + 36);
      rb0 = *(const float4*)(pb + ks + 32); rb1 = *(const float4*)(pb + ks + 36);
    }
    bf16x8 ah[4], al[4], bh[2], bl[2];
#pragma unroll
    for (int g = 0; g < 4; ++g) {
      ah[g] = AhV[((wy >> 4) + g) * 64 + lane];
      al[g] = AlV[((wy >> 4) + g) * 64 + lane];
    }
#pragma unroll
    for (int g = 0; g < 2; ++g) {
      bh[g] = BhV[((wx >> 4) + g) * 64 + lane];
      bl[g] = BlV[((wx >> 4) + g) * 64 + lane];
    }
#pragma unroll
    for (int i = 0; i < 4; ++i)
#pragma unroll
      for (int j = 0; j < 2; ++j) {
        acc[i][j] = __builtin_amdgcn_mfma_f32_16x16x32_bf16(ah[i], bh[j], acc[i][j], 0, 0, 0);
        acc[i][j] = __builtin_amdgcn_mfma_f32_16x16x32_bf16(al[i], bh[j], acc[i][j], 0, 0, 0);
        acc[i][j] = __builtin_amdgcn_mfma_f32_16x16x32_bf16(ah[i], bl[j], acc[i][j], 0, 0, 0);
      }
    __syncthreads();
  }

  const int r4 = (lane >> 4) * 4, fc = lane & 15;
#pragma unroll
  for (int i = 0; i < 4; ++i) {
    const int grow = ti * 128 + wy + i * 16 + r4;
#pragma unroll
    for (int j = 0; j < 2; ++j) {
      const int gcol = tj * 128 + wx + j * 16 + fc;
      float v[4];
#pragma unroll
      for (int r = 0; r < 4; ++r) v[r] = acc[i][j][r];
      if (mode) {
#pragma unroll
        for (int r = 0; r < 4; ++r)
          v[r] = 1.5f * E[(size_t)(grow + r) * 512 + gcol] - 0.5f * v[r];
      }
#pragma unroll
      for (int r = 0; r < 4; ++r) C[(size_t)(grow + r) * 512 + gcol] = v[r];
      if (ti != tj) {   // mirror (C symmetric); grow%4==0 -> 16B aligned
        float4 mv = make_float4(v[0], v[1], v[2], v[3]);
        *(float4*)&C[(size_t)gcol * 512 + grow] = mv;
      }
    }
  }
}

// Y1 = 1.5*Y0 - 0.5*Y0@Y0   (iteration 0, where W = Z0@Y0 = Y0). grid (10,2)
__global__ __launch_bounds__(512, 2) void k_ns_first(const float* __restrict__ Y0,
                                                     float* __restrict__ Y1) {
  const int mat = blockIdx.y;
  const float* a = Y0 + (size_t)mat * MATF;
  ns_gemm(a, a, a, Y1 + (size_t)mat * MATF, 1);
}

// W = Z@Y. grid (10,2)
__global__ __launch_bounds__(512, 2) void k_ns_W(const float* __restrict__ Y,
                                                 const float* __restrict__ Z,
                                                 float* __restrict__ W) {
  const int mat = blockIdx.y;
  ns_gemm(Z + (size_t)mat * MATF, Y + (size_t)mat * MATF, nullptr,
          W + (size_t)mat * MATF, 0);
}

// Yn = 1.5Y - 0.5*Y@W ; Zn = 1.5Z - 0.5*W@Z. grid (10,4): y = mat*2+which
__global__ __launch_bounds__(512, 2) void k_ns_YZ(const float* __restrict__ Y,
                                                  const float* __restrict__ Z,
                                                  const float* __restrict__ W,
                                                  float* __restrict__ Yn,
                                                  float* __restrict__ Zn) {
  const int mat = blockIdx.y >> 1, which = blockIdx.y & 1;
  const float* Wp = W + (size_t)mat * MATF;
  if (which == 0) {
    const float* Yp = Y + (size_t)mat * MATF;
    ns_gemm(Yp, Wp, Yp, Yn + (size_t)mat * MATF, 1);
  } else {
    const float* Zp = Z + (size_t)mat * MATF;
    ns_gemm(Wp, Zp, Zp, Zn + (size_t)mat * MATF, 1);
  }
}

// cross = sum_ij YA[i,j]*YB[j,i] in fp64. grid 256.
__global__ __launch_bounds__(256) void k_cross(const float* __restrict__ Y,
                                               double* __restrict__ S) {
  const float* YA = Y;
  const float* YB = Y + MATF;
  const int base = (blockIdx.x * 256 + threadIdx.x) * 4;
  double s = 0.0;
#pragma unroll
  for (int r = 0; r < 4; ++r) {
    const int id = base + r;
    const int i = id >> 9, j = id & 511;
    s += (double)YA[id] * (double)YB[j * 512 + i];
  }
  __shared__ double sm[256];
  sm[threadIdx.x] = s;
  __syncthreads();
  for (int o = 128; o > 0; o >>= 1) {
    if (threadIdx.x < o) sm[threadIdx.x] += sm[threadIdx.x + o];
    __syncthreads();
  }
  if (threadIdx.x == 0) atomicAdd(&S[4], sm[0]);
}

__global__ __launch_bounds__(256) void k_final(const float* __restrict__ M,
                                               const double* __restrict__ S,
                                               float* __restrict__ out) {
  double s = 0.0;
  for (int i = threadIdx.x; i < 512; i += 256) {
    double d = (double)M[i] - (double)M[512 + i];
    s += d * d;
  }
  __shared__ double sm[256];
  sm[threadIdx.x] = s;
  __syncthreads();
  for (int o = 128; o > 0; o >>= 1) {
    if (threadIdx.x < o) sm[threadIdx.x] += sm[threadIdx.x + o];
    __syncthreads();
  }
  if (threadIdx.x == 0) {
    double scale = sqrt(sqrt(S[0]) * sqrt(S[1]));
    double loss = sm[0] + S[2] + S[3] - 2.0 * scale * S[4];
    out[0] = (float)(loss / 512.0);
  }
}

extern "C" void kernel_launch(void* const* d_in, const int* in_sizes, int n_in,
                              void* d_out, int out_size, void* d_ws, size_t ws_size,
                              hipStream_t stream) {
  const float* X = (const float*)d_in[0];
  const float* Xt = (const float*)d_in[1];
  char* wsb = (char*)d_ws;
  float* Mv = (float*)wsb;
  double* S = (double*)(wsb + 4096);
  float* G = (float*)(wsb + 8192);
  float* big = (float*)(wsb + 8192 + 2 * (size_t)MATF * 4);

  // split-K factor for the gram: 32 if the workspace can hold the partials
  const size_t need32 = 8192 + 2 * (size_t)MATF * 4 + 2 * 32 * (size_t)MATF * 4;
  const int nk = (ws_size >= need32) ? 32 : 16;

  float* Gp = big;                                  // 2*nk MB, dead after k_gfin
  float* Yb[2] = { big, big + 2 * (size_t)MATF };   // each 2 MB (2 mats)
  float* Zb[2] = { big + 4 * (size_t)MATF, big + 6 * (size_t)MATF };
  float* W = big + 8 * (size_t)MATF;                // 2 mats

  hipMemsetAsync(S, 0, 16 * sizeof(double), stream);
  k_means<<<dim3(512, 2), 256, 0, stream>>>(X, Xt, Mv);
  k_gram<<<dim3(10, nk, 2), 256, 0, stream>>>(X, Xt, Gp, nk);
  k_gfin<<<dim3(1024, 2), 256, 0, stream>>>(Gp, Mv, G, S, nk);
  k_nsinit<<<dim3(1024, 2), 256, 0, stream>>>(G, Yb[0], Zb[1], S);
  k_ns_first<<<dim3(10, 2), 512, 0, stream>>>(Yb[0], Yb[1]);
  int cur = 1;
  for (int it = 1; it < 15; ++it) {
    k_ns_W<<<dim3(10, 2), 512, 0, stream>>>(Yb[cur], Zb[cur], W);
    k_ns_YZ<<<dim3(10, 4), 512, 0, stream>>>(Yb[cur], Zb[cur], W, Yb[1 - cur], Zb[1 - cur]);
    cur ^= 1;
  }
  k_cross<<<dim3(256), 256, 0, stream>>>(Yb[cur], S);
  k_final<<<dim3(1), 256, 0, stream>>>(Mv, S, (float*)d_out);
}